// Round 11
// baseline (22571.994 us; speedup 1.0000x reference)
//
#include <hip/hip_runtime.h>

static constexpr int Bsz  = 256;   // batch
static constexpr int Tseq = 256;   // timesteps
static constexpr int Hd   = 512;   // d_model
static constexpr int Ein  = 64;    // enc_in
static constexpr int NBLK = 256;   // 16 stripes x 16 colgroups
static constexpr int NTHR = 512;   // 8 waves

typedef __attribute__((ext_vector_type(8))) short bf16x8;
typedef __attribute__((ext_vector_type(4))) float f32x4;
typedef unsigned long long u64;

__device__ __forceinline__ float sigm(float x) { return 1.f / (1.f + expf(-x)); }
__device__ __forceinline__ short f2bf(float f) {
  union { float f; unsigned u; } v; v.f = f;
  unsigned r = v.u + 0x7FFFu + ((v.u >> 16) & 1u);
  return (short)(r >> 16);
}
__device__ __forceinline__ float bf2f(short s) {
  union { float f; unsigned u; } v; v.u = ((unsigned)(unsigned short)s) << 16; return v.f;
}

// ---- LLC-coherent (sc0 sc1) state access ----------------------------------
__device__ __forceinline__ void llc_ld4(f32x4& d, const float* p) {
  asm volatile("global_load_dwordx4 %0, %1, off sc0 sc1" : "=v"(d) : "v"(p));
}
__device__ __forceinline__ void llc_st1(float* p, float v) {
  asm volatile("global_store_dword %0, %1, off sc0 sc1" :: "v"(p), "v"(v) : "memory");
}
__device__ __forceinline__ void vwait() {
  asm volatile("s_waitcnt vmcnt(0)" ::: "memory");
  __builtin_amdgcn_sched_barrier(0);
}

struct KP {
  const float *x, *ba, *bna, *bma, *bm, *bhm;
  const short *Wh[13], *Wl[13];  // 0 Wa,1 Ua,2 Wna,3 Una,4 WAt,5 UAt,6 VAt,7 Wma,8 Uma,9 Wm,10 Um,11 Whm,12 Uhm
  float *Hbuf, *Nst, *NrA, *s1, *score, *mbuf, *mrM, *out;
  unsigned* cnt;
};

// ---------------------------------------------------------------------------
// Weight prepack (verified r4-r10): fp32 [K][N] -> fragment-major bf16 hi/lo.
// Weights are NOT swizzled (separate address space from A-LDS).
// ---------------------------------------------------------------------------
__global__ __launch_bounds__(256)
void prepack(const float* __restrict__ W, short* __restrict__ Whi,
             short* __restrict__ Wlo, int N)
{
  __shared__ float lds[32][257];
  const int tid = threadIdx.x;
  const int k0 = blockIdx.y * 32;
  const int n0 = blockIdx.x * 256;
  #pragma unroll
  for (int i = 0; i < 8; ++i) {
    const int flat = (i * 256 + tid) * 4;
    const int r = flat >> 8, c = flat & 255;
    const float4 v = *(const float4*)(W + (size_t)(k0 + r) * N + n0 + c);
    lds[r][c] = v.x; lds[r][c + 1] = v.y; lds[r][c + 2] = v.z; lds[r][c + 3] = v.w;
  }
  __syncthreads();
  const int lane = tid & 63, wv = tid >> 6;
  const int kr = (lane >> 4) * 8;
  const int cc = lane & 15;
  for (int nt = wv; nt < 16; nt += 4) {
    const int ntg = (n0 >> 4) + nt;
    const size_t off = ((size_t)((k0 >> 5) * (N >> 4) + ntg) * 64 + lane) * 8;
    bf16x8 vh, vl;
    #pragma unroll
    for (int j = 0; j < 8; ++j) {
      const float v = lds[kr + j][nt * 16 + cc];
      const short hb = f2bf(v);
      vh[j] = hb; vl[j] = f2bf(v - bf2f(hb));
    }
    *(bf16x8*)(Whi + off) = vh;
    *(bf16x8*)(Wlo + off) = vl;
  }
}

// A-LDS swizzled short-index for task t: spreads writes across bank quads,
// stays a within-1KB bijection for the lane-linear MFMA read.
__device__ __forceinline__ int aoff(int task) {
  return (task << 3) ^ (((task >> 4) & 7) << 3);
}
__device__ __forceinline__ void task_write(int task, f32x4 u0, f32x4 u1,
                                           short* hi, short* lo) {
  const int o = aoff(task);
  bf16x8 vh, vl;
  #pragma unroll
  for (int j = 0; j < 4; ++j) {
    const short h0 = f2bf(u0[j]); vh[j]     = h0; vl[j]     = f2bf(u0[j] - bf2f(h0));
    const short h1 = f2bf(u1[j]); vh[j + 4] = h1; vl[j + 4] = f2bf(u1[j] - bf2f(h1));
  }
  *(bf16x8*)(hi + o) = vh;
  *(bf16x8*)(lo + o) = vl;
}

// Contiguous slice staging: wave w reads rows w and w+8 as full 2KB streams.
// Lane l owns k = l*8..l*8+7 -> task ((l>>2)<<6)|row|((l&3)<<4).
__device__ __forceinline__ void stageSlice(const float* src, short* hi, short* lo,
                                           int wid, int lane) {
  const int ra = wid, rb = wid + 8;
  const float* pa = src + (ra << 9) + (lane << 3);
  const float* pb = src + (rb << 9) + (lane << 3);
  f32x4 a0, a1, b0, b1;
  llc_ld4(a0, pa); llc_ld4(a1, pa + 4);
  llc_ld4(b0, pb); llc_ld4(b1, pb + 4);
  vwait();
  const int tbase = ((lane >> 2) << 6) | ((lane & 3) << 4);
  task_write(tbase | ra, a0, a1, hi, lo);
  task_write(tbase | rb, b0, b1, hi, lo);
}

// MFMA over kc range, 3-term hi/lo split (~fp24). A-reads via aoff (swizzled).
__device__ __forceinline__ void mm(const short* Ah, const short* Al,
                                   const short* __restrict__ Wh,
                                   const short* __restrict__ Wl,
                                   int ntN, int ntg, int kc0, int kc1,
                                   int lane, f32x4& acc)
{
  for (int kc = kc0; kc < kc1; ++kc) {
    const int ao = aoff((kc << 6) | lane);
    const bf16x8 ah = *(const bf16x8*)(Ah + ao);
    const bf16x8 al = *(const bf16x8*)(Al + ao);
    const size_t o = ((size_t)((kc * ntN + ntg) << 6 | lane)) << 3;
    const bf16x8 bh = *(const bf16x8*)(Wh + o);
    const bf16x8 bl = *(const bf16x8*)(Wl + o);
    acc = __builtin_amdgcn_mfma_f32_16x16x32_bf16(ah, bh, acc, 0, 0, 0);
    acc = __builtin_amdgcn_mfma_f32_16x16x32_bf16(al, bh, acc, 0, 0, 0);
    acc = __builtin_amdgcn_mfma_f32_16x16x32_bf16(ah, bl, acc, 0, 0, 0);
  }
}

// Per-stripe barrier: 16 blocks; relaxed agent atomics; s_sleep(4) backoff.
__device__ __forceinline__ void gbar(unsigned* cnt, int stripe, unsigned& ph) {
  asm volatile("s_waitcnt vmcnt(0)" ::: "memory");
  __syncthreads();
  ++ph;
  if (threadIdx.x == 0) {
    __hip_atomic_fetch_add(&cnt[stripe << 4], 1u, __ATOMIC_RELAXED,
                           __HIP_MEMORY_SCOPE_AGENT);
    const unsigned tgt = ph * 16u;
    while (__hip_atomic_load(&cnt[stripe << 4], __ATOMIC_RELAXED,
                             __HIP_MEMORY_SCOPE_AGENT) < tgt)
      __builtin_amdgcn_s_sleep(4);
  }
  __syncthreads();
}

// ---------------------------------------------------------------------------
// Persistent kernel: 256 blocks = 16 stripes(16 rows) x 16 colgroups(32 cols).
// Contiguous sc-staging; swizzled A-LDS; register zA/zM/m/N/h; 7 barriers/step.
// ---------------------------------------------------------------------------
__global__ __launch_bounds__(NTHR, 1)
void dtgru(KP P)
{
  __shared__ short sAh[8192], sAl[8192];   // dt (P1-P2) / m (P6)
  __shared__ short sBh[8192], sBl[8192];   // N (P1) / NrA (P2) / N-new (P3..P5,next P1)
  __shared__ short sCh[8192], sCl[8192];   // s1 (P4) / Omega (P5) / mrM (P7)
  __shared__ short sDh[8192], sDl[8192];   // h(t-1)  [persists across step]
  __shared__ short sXh[1024], sXl[1024];   // x_t
  __shared__ float red[2048];
  const int tid = threadIdx.x, lane = tid & 63, wid = tid >> 6;
  const int bid = blockIdx.x;
  const int g = bid & 15;           // colgroup; XCD=bid%8
  const int stripe = bid >> 4;      // 0..15
  const int r0 = stripe << 4;       // 16 rows
  const int nt = wid & 1;
  const int q  = wid >> 1;          // 0..3 (N=512 phases)
  const int mat  = (wid >> 1) & 1;  // N=1024 phases
  const int half = wid >> 2;        //   "
  const int ntb = (g << 1) | nt;    // N=512 ntg
  const int col5 = (g << 5) | (nt << 4) | (lane & 15);
  const int rb = r0 + ((lane >> 4) << 2);
  unsigned ph = 0;
  float Nreg[4] = {0,0,0,0}, hreg[4] = {0,0,0,0};
  float zAreg[4] = {0,0,0,0}, zMreg[4] = {0,0,0,0}, mreg[4] = {0,0,0,0};
  const float b_az = P.ba[col5],  b_ar = P.ba[col5 + 512];
  const float b_na = P.bna[col5], b_ma = P.bma[col5];
  const float b_mz = P.bm[col5],  b_mr = P.bm[col5 + 512];
  const float b_hm = P.bhm[col5];

  for (int i = tid; i < 2048; i += NTHR) {       // zero persistent slots (B, D)
    ((u64*)sBh)[i] = 0; ((u64*)sBl)[i] = 0;
    ((u64*)sDh)[i] = 0; ((u64*)sDl)[i] = 0;
  }
  __syncthreads();

  #pragma clang loop unroll(disable)
  for (int t = 0; t < Tseq; ++t) {
    // ---- P1: gates_A = dt@Wa + N@Ua -> zA(reg), NrA(global) --------------
    {
      const int tbase = ((lane >> 2) << 6) | ((lane & 3) << 4);
      const int ra = wid, rbw = wid + 8;
      const float* Hr = P.Hbuf + (r0 << 9);
      const float* pa = Hr + (ra << 9) + (lane << 3);
      const float* pb = Hr + (rbw << 9) + (lane << 3);
      f32x4 u0, u1, v0, v1, x0 = {0,0,0,0}, x1 = {0,0,0,0};
      llc_ld4(u0, pa); llc_ld4(u1, pa + 4);
      llc_ld4(v0, pb); llc_ld4(v1, pb + 4);
      if (tid < 128) {
        const float* px = P.x + ((size_t)(r0 + (tid >> 3)) * Tseq + t) * Ein
                        + ((tid & 7) << 3);
        x0 = *(const f32x4*)px; x1 = *(const f32x4*)(px + 4);
      }
      vwait();
      {
        const int ta = tbase | ra;
        const int o = aoff(ta);
        const bf16x8 dh = *(const bf16x8*)(sDh + o), dlo = *(const bf16x8*)(sDl + o);
        f32x4 d0, d1;
        #pragma unroll
        for (int j = 0; j < 4; ++j) {
          d0[j] = u0[j] - (bf2f(dh[j])     + bf2f(dlo[j]));
          d1[j] = u1[j] - (bf2f(dh[j + 4]) + bf2f(dlo[j + 4]));
        }
        task_write(ta, d0, d1, sAh, sAl);
        task_write(ta, u0, u1, sDh, sDl);
      }
      {
        const int tb = tbase | rbw;
        const int o = aoff(tb);
        const bf16x8 dh = *(const bf16x8*)(sDh + o), dlo = *(const bf16x8*)(sDl + o);
        f32x4 d0, d1;
        #pragma unroll
        for (int j = 0; j < 4; ++j) {
          d0[j] = v0[j] - (bf2f(dh[j])     + bf2f(dlo[j]));
          d1[j] = v1[j] - (bf2f(dh[j + 4]) + bf2f(dlo[j + 4]));
        }
        task_write(tb, d0, d1, sAh, sAl);
        task_write(tb, v0, v1, sDh, sDl);
      }
      if (tid < 128) {
        const int tx = (((tid & 7) >> 2) << 6) | (tid >> 3) | ((tid & 3) << 4);
        task_write(tx, x0, x1, sXh, sXl);
      }
    }
    __syncthreads();
    {
      f32x4 acc = {0,0,0,0};
      const int ntg = (half ? 32 : 0) | ((g << 1) | nt);   // z / r half of N=1024
      if (!mat) mm(sAh, sAl, P.Wh[0], P.Wl[0], 64, ntg, 0, 16, lane, acc);  // dt@Wa
      else      mm(sBh, sBl, P.Wh[1], P.Wl[1], 64, ntg, 0, 16, lane, acc);  // N@Ua
      if (mat) *(f32x4*)&red[(((half << 1) | nt) << 8) | (lane << 2)] = acc;
      __syncthreads();
      if (!mat) acc += *(f32x4*)&red[(((half << 1) | nt) << 8) | (lane << 2)];
      __syncthreads();                       // red reuse fence
      if (!mat && half) *(f32x4*)&red[(nt << 8) | (lane << 2)] = acc;
      __syncthreads();
      if (!mat && !half) {
        const f32x4 ar = *(const f32x4*)&red[(nt << 8) | (lane << 2)];
        #pragma unroll
        for (int i = 0; i < 4; ++i) {
          zAreg[i] = sigm(acc[i] + b_az);
          const float rA = sigm(ar[i] + b_ar);
          llc_st1(&P.NrA[((rb + i) << 9) | col5], Nreg[i] * rA);
        }
      }
    }
    gbar(P.cnt, stripe, ph);

    // ---- P2: N = (1-zA)N + zA tanh(dt@Wna + NrA@Una + bna) ---------------
    stageSlice(P.NrA + (r0 << 9), sBh, sBl, wid, lane);
    __syncthreads();
    {
      f32x4 acc = {0,0,0,0};
      const int kc0 = (q & 1) << 3;
      if (!(q >> 1)) mm(sAh, sAl, P.Wh[2], P.Wl[2], 32, ntb, kc0, kc0 + 8, lane, acc);
      else           mm(sBh, sBl, P.Wh[3], P.Wl[3], 32, ntb, kc0, kc0 + 8, lane, acc);
      if (q) *(f32x4*)&red[((((q - 1) << 1) | nt) << 8) | (lane << 2)] = acc;
      __syncthreads();
      if (!q) {
        #pragma unroll
        for (int j = 0; j < 3; ++j) acc += *(f32x4*)&red[(((j << 1) | nt) << 8) | (lane << 2)];
        #pragma unroll
        for (int i = 0; i < 4; ++i) {
          const float hn = tanhf(acc[i] + b_na);
          const float Nn = (1.f - zAreg[i]) * Nreg[i] + zAreg[i] * hn;
          Nreg[i] = Nn;
          llc_st1(&P.Nst[((rb + i) << 9) | col5], Nn);
        }
      }
    }
    gbar(P.cnt, stripe, ph);

    // ---- P3: s1 = tanh(h@WAttn + N_new@UAttn) ----------------------------
    stageSlice(P.Nst + (r0 << 9), sBh, sBl, wid, lane);  // N-new -> slotB (persists)
    __syncthreads();
    {
      f32x4 acc = {0,0,0,0};
      const int kc0 = (q & 1) << 3;
      if (!(q >> 1)) mm(sDh, sDl, P.Wh[4], P.Wl[4], 32, ntb, kc0, kc0 + 8, lane, acc);
      else           mm(sBh, sBl, P.Wh[5], P.Wl[5], 32, ntb, kc0, kc0 + 8, lane, acc);
      if (q) *(f32x4*)&red[((((q - 1) << 1) | nt) << 8) | (lane << 2)] = acc;
      __syncthreads();
      if (!q) {
        #pragma unroll
        for (int j = 0; j < 3; ++j) acc += *(f32x4*)&red[(((j << 1) | nt) << 8) | (lane << 2)];
        #pragma unroll
        for (int i = 0; i < 4; ++i)
          llc_st1(&P.s1[((rb + i) << 9) | col5], tanhf(acc[i]));
      }
    }
    gbar(P.cnt, stripe, ph);

    // ---- P4: score = s1@VAttn --------------------------------------------
    stageSlice(P.s1 + (r0 << 9), sCh, sCl, wid, lane);
    __syncthreads();
    {
      f32x4 acc = {0,0,0,0};
      mm(sCh, sCl, P.Wh[6], P.Wl[6], 32, ntb, q << 2, (q << 2) + 4, lane, acc);
      if (q) *(f32x4*)&red[((((q - 1) << 1) | nt) << 8) | (lane << 2)] = acc;
      __syncthreads();
      if (!q) {
        #pragma unroll
        for (int j = 0; j < 3; ++j) acc += *(f32x4*)&red[(((j << 1) | nt) << 8) | (lane << 2)];
        #pragma unroll
        for (int i = 0; i < 4; ++i)
          llc_st1(&P.score[((rb + i) << 9) | col5], acc[i]);
      }
    }
    gbar(P.cnt, stripe, ph);

    // ---- P5: softmax+Omega (N from sB, Omega -> sC); m = tanh(...) -------
    {
      const int lr0 = wid << 1;
      f32x4 s00, s01, s10, s11;
      llc_ld4(s00, P.score + ((r0 + lr0) << 9) + (lane << 3));
      llc_ld4(s01, P.score + ((r0 + lr0) << 9) + (lane << 3) + 4);
      llc_ld4(s10, P.score + ((r0 + lr0 + 1) << 9) + (lane << 3));
      llc_ld4(s11, P.score + ((r0 + lr0 + 1) << 9) + (lane << 3) + 4);
      vwait();
      #pragma unroll
      for (int rr = 0; rr < 2; ++rr) {
        const int lr = lr0 | rr;
        const f32x4 v0 = rr ? s10 : s00, v1 = rr ? s11 : s01;
        float mx = v0[0];
        #pragma unroll
        for (int j = 1; j < 4; ++j) mx = fmaxf(mx, v0[j]);
        #pragma unroll
        for (int j = 0; j < 4; ++j) mx = fmaxf(mx, v1[j]);
        #pragma unroll
        for (int d = 1; d < 64; d <<= 1) mx = fmaxf(mx, __shfl_xor(mx, d));
        float e[8];
        #pragma unroll
        for (int j = 0; j < 4; ++j) { e[j] = expf(v0[j] - mx); e[j + 4] = expf(v1[j] - mx); }
        float sm = ((e[0] + e[1]) + (e[2] + e[3])) + ((e[4] + e[5]) + (e[6] + e[7]));
        #pragma unroll
        for (int d = 1; d < 64; d <<= 1) sm += __shfl_xor(sm, d);
        const float inv = 1.f / sm;
        const int o = aoff(((lane >> 2) << 6) | lr | ((lane & 3) << 4));
        const bf16x8 nh = *(const bf16x8*)(sBh + o), nl = *(const bf16x8*)(sBl + o);
        bf16x8 vh, vl;
        #pragma unroll
        for (int j = 0; j < 8; ++j) {
          const float om = e[j] * inv * (bf2f(nh[j]) + bf2f(nl[j]));
          const short hb = f2bf(om);
          vh[j] = hb; vl[j] = f2bf(om - bf2f(hb));
        }
        *(bf16x8*)(sCh + o) = vh;
        *(bf16x8*)(sCl + o) = vl;
      }
    }
    __syncthreads();
    {
      f32x4 acc = {0,0,0,0};
      const int kc0 = (q & 1) << 3;
      if (!(q >> 1)) mm(sCh, sCl, P.Wh[7], P.Wl[7], 32, ntb, kc0, kc0 + 8, lane, acc);  // Omega@Wma
      else           mm(sDh, sDl, P.Wh[8], P.Wl[8], 32, ntb, kc0, kc0 + 8, lane, acc);  // h@Uma
      if (q) *(f32x4*)&red[((((q - 1) << 1) | nt) << 8) | (lane << 2)] = acc;
      __syncthreads();
      if (!q) {
        #pragma unroll
        for (int j = 0; j < 3; ++j) acc += *(f32x4*)&red[(((j << 1) | nt) << 8) | (lane << 2)];
        #pragma unroll
        for (int i = 0; i < 4; ++i) {
          const float m = tanhf(acc[i] + b_ma);
          mreg[i] = m;
          llc_st1(&P.mbuf[((rb + i) << 9) | col5], m);
        }
      }
    }
    gbar(P.cnt, stripe, ph);

    // ---- P6: gates_M = x@Wm + m@Um -> zM(reg), mrM(global) ---------------
    stageSlice(P.mbuf + (r0 << 9), sAh, sAl, wid, lane);
    __syncthreads();
    {
      f32x4 acc = {0,0,0,0};
      const int ntg = (half ? 32 : 0) | ((g << 1) | nt);
      if (!mat) { mm(sXh, sXl, P.Wh[9],  P.Wl[9],  64, ntg, 0, 2, lane, acc);
                  mm(sAh, sAl, P.Wh[10], P.Wl[10], 64, ntg, 0, 7, lane, acc); }
      else      { mm(sAh, sAl, P.Wh[10], P.Wl[10], 64, ntg, 7, 16, lane, acc); }
      if (mat) *(f32x4*)&red[(((half << 1) | nt) << 8) | (lane << 2)] = acc;
      __syncthreads();
      if (!mat) acc += *(f32x4*)&red[(((half << 1) | nt) << 8) | (lane << 2)];
      __syncthreads();
      if (!mat && half) *(f32x4*)&red[(nt << 8) | (lane << 2)] = acc;
      __syncthreads();
      if (!mat && !half) {
        const f32x4 ar = *(const f32x4*)&red[(nt << 8) | (lane << 2)];
        #pragma unroll
        for (int i = 0; i < 4; ++i) {
          zMreg[i] = sigm(acc[i] + b_mz);
          const float rM = sigm(ar[i] + b_mr);
          llc_st1(&P.mrM[((rb + i) << 9) | col5], mreg[i] * rM);
        }
      }
    }
    gbar(P.cnt, stripe, ph);

    // ---- P7: h = (1-zM)h + zM tanh(x@Whm + mrM@Uhm + bhm) ----------------
    stageSlice(P.mrM + (r0 << 9), sCh, sCl, wid, lane);
    __syncthreads();
    {
      f32x4 acc = {0,0,0,0};
      if (q == 0)      { mm(sXh, sXl, P.Wh[11], P.Wl[11], 32, ntb, 0, 2, lane, acc);
                         mm(sCh, sCl, P.Wh[12], P.Wl[12], 32, ntb, 0, 2, lane, acc); }
      else if (q == 1)   mm(sCh, sCl, P.Wh[12], P.Wl[12], 32, ntb, 2, 7, lane, acc);
      else if (q == 2)   mm(sCh, sCl, P.Wh[12], P.Wl[12], 32, ntb, 7, 12, lane, acc);
      else               mm(sCh, sCl, P.Wh[12], P.Wl[12], 32, ntb, 12, 16, lane, acc);
      if (q) *(f32x4*)&red[((((q - 1) << 1) | nt) << 8) | (lane << 2)] = acc;
      __syncthreads();
      if (!q) {
        #pragma unroll
        for (int j = 0; j < 3; ++j) acc += *(f32x4*)&red[(((j << 1) | nt) << 8) | (lane << 2)];
        #pragma unroll
        for (int i = 0; i < 4; ++i) {
          const float hh = tanhf(acc[i] + b_hm);
          const float hn = (1.f - zMreg[i]) * hreg[i] + zMreg[i] * hh;
          hreg[i] = hn;
          llc_st1(&P.Hbuf[((rb + i) << 9) | col5], hn);
          P.out[((((size_t)(rb + i)) << 8 | t) << 9) | col5] = hn;
        }
      }
    }
    gbar(P.cnt, stripe, ph);
  }
}

__global__ __launch_bounds__(256)
void initk(float* hbuf, unsigned* cnt) {
  const int i = blockIdx.x * 256 + threadIdx.x;
  hbuf[i] = 0.f;
  if (blockIdx.x == 0) cnt[threadIdx.x] = 0u;
}

__global__ __launch_bounds__(256)
void finalize(const float* __restrict__ hT, const float* __restrict__ nT,
              float* __restrict__ oh, float* __restrict__ on) {
  const int i = blockIdx.x * 256 + threadIdx.x;
  f32x4 a, b;
  asm volatile("global_load_dword %0, %1, off sc0 sc1" : "=v"(a[0]) : "v"(&hT[i]));
  asm volatile("global_load_dword %0, %1, off sc0 sc1" : "=v"(b[0]) : "v"(&nT[i]));
  vwait();
  oh[i] = a[0]; on[i] = b[0];
}

extern "C" void kernel_launch(void* const* d_in, const int* in_sizes, int n_in,
                              void* d_out, int out_size, void* d_ws, size_t ws_size,
                              hipStream_t stream)
{
  (void)in_sizes; (void)n_in; (void)out_size; (void)ws_size;

  unsigned* cnt = (unsigned*)d_ws;          // 16 stripe counters, 64B apart
  float* w = (float*)d_ws + 256;
  const int S = Bsz * Hd;                   // 131072

  KP P{};
  P.x   = (const float*)d_in[0];
  P.ba  = (const float*)d_in[3];
  P.bna = (const float*)d_in[6];
  P.bma = (const float*)d_in[12];
  P.bm  = (const float*)d_in[15];
  P.bhm = (const float*)d_in[18];
  P.Hbuf = w;          P.Nst = w + S;      P.NrA = w + 2 * S;
  P.s1   = w + 3 * S;  P.score = w + 4 * S;
  P.mbuf = w + 5 * S;  P.mrM = w + 6 * S;
  P.out = (float*)d_out;
  P.cnt = cnt;
  float* out_hT = P.out + (size_t)Bsz * Tseq * Hd;
  float* out_NT = out_hT + S;

  short* wpk = (short*)(w + 7 * S);
  const int widx[13] = {1, 2, 4, 5, 7, 8, 9, 10, 11, 13, 14, 16, 17};
  const int wK[13]   = {512, 512, 512, 512, 512, 512, 512, 512, 512, 64, 512, 64, 512};
  const int wN[13]   = {1024, 1024, 512, 512, 512, 512, 512, 512, 512, 1024, 1024, 512, 512};
  {
    size_t off = 0;
    for (int i = 0; i < 13; ++i) {
      const size_t sz = (size_t)wK[i] * wN[i];
      P.Wh[i] = wpk + off; off += sz;
      P.Wl[i] = wpk + off; off += sz;
    }
  }
  for (int i = 0; i < 13; ++i) {
    dim3 gg(wN[i] / 256, wK[i] / 32);
    prepack<<<gg, 256, 0, stream>>>((const float*)d_in[widx[i]],
                                    (short*)P.Wh[i], (short*)P.Wl[i], wN[i]);
  }

  initk<<<S / 256, 256, 0, stream>>>(P.Hbuf, cnt);

  dtgru<<<NBLK, NTHR, 0, stream>>>(P);

  finalize<<<S / 256, 256, 0, stream>>>(P.Hbuf, P.Nst, out_hT, out_NT);
}

// Round 12
// 21716.168 us; speedup vs baseline: 1.0394x; 1.0394x over previous
//
#include <hip/hip_runtime.h>

static constexpr int Bsz  = 256;   // batch
static constexpr int Tseq = 256;   // timesteps
static constexpr int Hd   = 512;   // d_model
static constexpr int Ein  = 64;    // enc_in
static constexpr int NBLK = 256;   // 16 stripes x 16 colgroups
static constexpr int NTHR = 512;   // 8 waves

typedef __attribute__((ext_vector_type(8))) short bf16x8;
typedef __attribute__((ext_vector_type(4))) float f32x4;
typedef unsigned long long u64;

__device__ __forceinline__ float sigm(float x) { return 1.f / (1.f + expf(-x)); }
__device__ __forceinline__ short f2bf(float f) {
  union { float f; unsigned u; } v; v.f = f;
  unsigned r = v.u + 0x7FFFu + ((v.u >> 16) & 1u);
  return (short)(r >> 16);
}
__device__ __forceinline__ float bf2f(short s) {
  union { float f; unsigned u; } v; v.u = ((unsigned)(unsigned short)s) << 16; return v.f;
}

// ---- LLC-coherent (sc0 sc1): bypass L1/L2, serialize at LLC ----------------
__device__ __forceinline__ void llc_ld4(f32x4& d, const float* p) {
  asm volatile("global_load_dwordx4 %0, %1, off sc0 sc1" : "=v"(d) : "v"(p));
}
__device__ __forceinline__ void llc_st1(float* p, float v) {
  asm volatile("global_store_dword %0, %1, off sc0 sc1" :: "v"(p), "v"(v) : "memory");
}
// ---- XCD-L2-coherent (sc0 only): bypass L1, hit shared L2 ------------------
__device__ __forceinline__ void l2_ld4(f32x4& d, const float* p) {
  asm volatile("global_load_dwordx4 %0, %1, off sc0" : "=v"(d) : "v"(p));
}
__device__ __forceinline__ void l2_st4(float* p, f32x4 v) {
  asm volatile("global_store_dwordx4 %0, %1, off sc0" :: "v"(p), "v"(v) : "memory");
}
__device__ __forceinline__ void vwait() {
  asm volatile("s_waitcnt vmcnt(0)" ::: "memory");
  __builtin_amdgcn_sched_barrier(0);
}

struct KP {
  const float *x, *ba, *bna, *bma, *bm, *bhm;
  const short *Wh[13], *Wl[13];  // 0 Wa,1 Ua,2 Wna,3 Una,4 WAt,5 UAt,6 VAt,7 Wma,8 Uma,9 Wm,10 Um,11 Whm,12 Uhm
  float *Hbuf, *Nst, *NrA, *s1, *score, *mbuf, *mrM, *out;
  float* pairbuf;
  unsigned* cnt;
};

// ---------------------------------------------------------------------------
// Weight prepack (verified r4-r11): fp32 [K][N] -> fragment-major bf16 hi/lo.
// ---------------------------------------------------------------------------
__global__ __launch_bounds__(256)
void prepack(const float* __restrict__ W, short* __restrict__ Whi,
             short* __restrict__ Wlo, int N)
{
  __shared__ float lds[32][257];
  const int tid = threadIdx.x;
  const int k0 = blockIdx.y * 32;
  const int n0 = blockIdx.x * 256;
  #pragma unroll
  for (int i = 0; i < 8; ++i) {
    const int flat = (i * 256 + tid) * 4;
    const int r = flat >> 8, c = flat & 255;
    const float4 v = *(const float4*)(W + (size_t)(k0 + r) * N + n0 + c);
    lds[r][c] = v.x; lds[r][c + 1] = v.y; lds[r][c + 2] = v.z; lds[r][c + 3] = v.w;
  }
  __syncthreads();
  const int lane = tid & 63, wv = tid >> 6;
  const int kr = (lane >> 4) * 8;
  const int cc = lane & 15;
  for (int nt = wv; nt < 16; nt += 4) {
    const int ntg = (n0 >> 4) + nt;
    const size_t off = ((size_t)((k0 >> 5) * (N >> 4) + ntg) * 64 + lane) * 8;
    bf16x8 vh, vl;
    #pragma unroll
    for (int j = 0; j < 8; ++j) {
      const float v = lds[kr + j][nt * 16 + cc];
      const short hb = f2bf(v);
      vh[j] = hb; vl[j] = f2bf(v - bf2f(hb));
    }
    *(bf16x8*)(Whi + off) = vh;
    *(bf16x8*)(Wlo + off) = vl;
  }
}

// A-LDS swizzle (r11-verified): conflict-free writes, bijective for MFMA reads.
__device__ __forceinline__ int aoff(int task) {
  return (task << 3) ^ (((task >> 4) & 7) << 3);
}
__device__ __forceinline__ void task_write(int task, f32x4 u0, f32x4 u1,
                                           short* hi, short* lo) {
  const int o = aoff(task);
  bf16x8 vh, vl;
  #pragma unroll
  for (int j = 0; j < 4; ++j) {
    const short h0 = f2bf(u0[j]); vh[j]     = h0; vl[j]     = f2bf(u0[j] - bf2f(h0));
    const short h1 = f2bf(u1[j]); vh[j + 4] = h1; vl[j + 4] = f2bf(u1[j] - bf2f(h1));
  }
  *(bf16x8*)(hi + o) = vh;
  *(bf16x8*)(lo + o) = vl;
}

// ---- Pair-relay context: blocks (stripe,g) and (stripe,g^8) share an XCD. --
struct PairCtx {
  float* mybuf; const float* pbuf;
  unsigned *myflag, *pflag;
  unsigned pfc;
  int relay, myhalf;
};

__device__ __forceinline__ void pairWait(PairCtx& C, int tid) {
  asm volatile("s_waitcnt vmcnt(0)" ::: "memory");  // my L2 stores complete
  __syncthreads();
  C.pfc++;
  if (tid == 0) {
    __hip_atomic_fetch_add(C.myflag, 1u, __ATOMIC_RELAXED, __HIP_MEMORY_SCOPE_AGENT);
    while (__hip_atomic_load(C.pflag, __ATOMIC_RELAXED, __HIP_MEMORY_SCOPE_AGENT) < C.pfc)
      __builtin_amdgcn_s_sleep(2);
  }
  __syncthreads();
}

// Stage one 16x512 fp32 slice into LDS fragments. Relay: each member loads 8
// rows from LLC and swaps halves through the shared XCD L2.
__device__ __forceinline__ void pairStage(const float* src, short* hi, short* lo,
                                          PairCtx& C, int wid, int lane, int tid) {
  const int tb = ((lane >> 2) << 6) | ((lane & 3) << 4);
  if (C.relay) {
    const int mrow = (C.myhalf << 3) | wid;
    const float* p = src + (mrow << 9) + (lane << 3);
    f32x4 a0, a1; llc_ld4(a0, p); llc_ld4(a1, p + 4); vwait();
    task_write(tb | mrow, a0, a1, hi, lo);
    float* q = C.mybuf + (wid << 9) + (lane << 3);
    l2_st4(q, a0); l2_st4(q + 4, a1);
    pairWait(C, tid);
    const int prow = ((C.myhalf ^ 1) << 3) | wid;
    const float* r = C.pbuf + (wid << 9) + (lane << 3);
    f32x4 b0, b1; l2_ld4(b0, r); l2_ld4(b1, r + 4); vwait();
    task_write(tb | prow, b0, b1, hi, lo);
  } else {
    const float* pa = src + (wid << 9) + (lane << 3);
    const float* pb = src + ((wid + 8) << 9) + (lane << 3);
    f32x4 a0, a1, b0, b1;
    llc_ld4(a0, pa); llc_ld4(a1, pa + 4);
    llc_ld4(b0, pb); llc_ld4(b1, pb + 4);
    vwait();
    task_write(tb | wid, a0, a1, hi, lo);
    task_write(tb | (wid + 8), b0, b1, hi, lo);
  }
}

// MFMA over kc range, 3-term hi/lo split (~fp24).
__device__ __forceinline__ void mm(const short* Ah, const short* Al,
                                   const short* __restrict__ Wh,
                                   const short* __restrict__ Wl,
                                   int ntN, int ntg, int kc0, int kc1,
                                   int lane, f32x4& acc)
{
  for (int kc = kc0; kc < kc1; ++kc) {
    const int ao = aoff((kc << 6) | lane);
    const bf16x8 ah = *(const bf16x8*)(Ah + ao);
    const bf16x8 al = *(const bf16x8*)(Al + ao);
    const size_t o = ((size_t)((kc * ntN + ntg) << 6 | lane)) << 3;
    const bf16x8 bh = *(const bf16x8*)(Wh + o);
    const bf16x8 bl = *(const bf16x8*)(Wl + o);
    acc = __builtin_amdgcn_mfma_f32_16x16x32_bf16(ah, bh, acc, 0, 0, 0);
    acc = __builtin_amdgcn_mfma_f32_16x16x32_bf16(al, bh, acc, 0, 0, 0);
    acc = __builtin_amdgcn_mfma_f32_16x16x32_bf16(ah, bl, acc, 0, 0, 0);
  }
}

// Per-stripe barrier (r10-verified).
__device__ __forceinline__ void gbar(unsigned* cnt, int stripe, unsigned& ph) {
  asm volatile("s_waitcnt vmcnt(0)" ::: "memory");
  __syncthreads();
  ++ph;
  if (threadIdx.x == 0) {
    __hip_atomic_fetch_add(&cnt[stripe << 4], 1u, __ATOMIC_RELAXED,
                           __HIP_MEMORY_SCOPE_AGENT);
    const unsigned tgt = ph * 16u;
    while (__hip_atomic_load(&cnt[stripe << 4], __ATOMIC_RELAXED,
                             __HIP_MEMORY_SCOPE_AGENT) < tgt)
      __builtin_amdgcn_s_sleep(4);
  }
  __syncthreads();
}

// ---------------------------------------------------------------------------
// Persistent kernel: 256 blocks = 16 stripes x 16 colgroups; pair-relay
// staging through XCD L2; register zA/zM/m/N/h; 7 barriers/step.
// ---------------------------------------------------------------------------
__global__ __launch_bounds__(NTHR, 1)
void dtgru(KP P)
{
  __shared__ short sAh[8192], sAl[8192];   // dt (P1-P2) / score-f32 (P5) / m (P6)
  __shared__ short sBh[8192], sBl[8192];   // N (P1) / NrA (P2) / N-new (P3..P5,next P1)
  __shared__ short sCh[8192], sCl[8192];   // s1 (P4) / Omega (P5) / mrM (P7)
  __shared__ short sDh[8192], sDl[8192];   // h(t-1) [persists]
  __shared__ short sXh[1024], sXl[1024];   // x_t
  __shared__ float red[2048];
  __shared__ int s_relay;
  const int tid = threadIdx.x, lane = tid & 63, wid = tid >> 6;
  const int bid = blockIdx.x;
  const int g = bid & 15;
  const int stripe = bid >> 4;
  const int r0 = stripe << 4;
  const int nt = wid & 1;
  const int q  = wid >> 1;
  const int mat  = (wid >> 1) & 1;
  const int half = wid >> 2;
  const int ntb = (g << 1) | nt;
  const int col5 = (g << 5) | (nt << 4) | (lane & 15);
  const int rb = r0 + ((lane >> 4) << 2);
  unsigned ph = 0;
  float Nreg[4] = {0,0,0,0}, hreg[4] = {0,0,0,0};
  float zAreg[4] = {0,0,0,0}, zMreg[4] = {0,0,0,0}, mreg[4] = {0,0,0,0};
  const float b_az = P.ba[col5],  b_ar = P.ba[col5 + 512];
  const float b_na = P.bna[col5], b_ma = P.bma[col5];
  const float b_mz = P.bm[col5],  b_mr = P.bm[col5 + 512];
  const float b_hm = P.bhm[col5];

  // ---- pair setup + runtime XCD verification -----------------------------
  const int member = g >> 3;
  const int pairid = (stripe << 3) | (g & 7);
  unsigned* pbase = P.cnt + 256 + (pairid << 4);
  PairCtx C;
  C.myflag = pbase + (member << 2);
  C.pflag  = pbase + ((member ^ 1) << 2);
  C.mybuf  = P.pairbuf + ((size_t)((pairid << 1) | member) << 12);
  C.pbuf   = P.pairbuf + ((size_t)((pairid << 1) | (member ^ 1)) << 12);
  C.pfc = 0; C.myhalf = member;
  unsigned my_xcc = 0xFFFFu;
  asm volatile("s_getreg_b32 %0, hwreg(HW_REG_XCC_ID)" : "=s"(my_xcc));
  if (tid == 0)
    __hip_atomic_store(pbase + 8 + (member << 1), my_xcc + 1u,
                       __ATOMIC_RELAXED, __HIP_MEMORY_SCOPE_AGENT);

  for (int i = tid; i < 2048; i += NTHR) {       // zero persistent slots (B, D)
    ((u64*)sBh)[i] = 0; ((u64*)sBl)[i] = 0;
    ((u64*)sDh)[i] = 0; ((u64*)sDl)[i] = 0;
  }
  gbar(P.cnt, stripe, ph);                        // publish xcc (+ LDS zero fence)
  if (tid == 0) {
    const unsigned px = __hip_atomic_load(pbase + 8 + ((member ^ 1) << 1),
                                          __ATOMIC_RELAXED, __HIP_MEMORY_SCOPE_AGENT);
    s_relay = (my_xcc < 8u && px == my_xcc + 1u) ? 1 : 0;
  }
  __syncthreads();
  C.relay = s_relay;

  #pragma clang loop unroll(disable)
  for (int t = 0; t < Tseq; ++t) {
    // ---- P1: gates_A = dt@Wa + N@Ua -> zA(reg), NrA(global) --------------
    {
      f32x4 x0 = {0,0,0,0}, x1 = {0,0,0,0};
      if (tid < 128) {                            // x: normal cached loads
        const float* px = P.x + ((size_t)(r0 + (tid >> 3)) * Tseq + t) * Ein
                        + ((tid & 7) << 3);
        x0 = *(const f32x4*)px; x1 = *(const f32x4*)(px + 4);
      }
      const int tb = ((lane >> 2) << 6) | ((lane & 3) << 4);
      const float* Hr = P.Hbuf + (r0 << 9);
      // p1 write: dt -> sA, h -> sD (per-task, owner-thread stable)
      auto p1w = [&](int task, f32x4 u0, f32x4 u1) {
        const int o = aoff(task);
        const bf16x8 dh = *(const bf16x8*)(sDh + o), dlo = *(const bf16x8*)(sDl + o);
        f32x4 d0, d1;
        #pragma unroll
        for (int j = 0; j < 4; ++j) {
          d0[j] = u0[j] - (bf2f(dh[j])     + bf2f(dlo[j]));
          d1[j] = u1[j] - (bf2f(dh[j + 4]) + bf2f(dlo[j + 4]));
        }
        task_write(task, d0, d1, sAh, sAl);
        task_write(task, u0, u1, sDh, sDl);
      };
      if (C.relay) {
        const int mrow = (C.myhalf << 3) | wid;
        const float* p = Hr + (mrow << 9) + (lane << 3);
        f32x4 a0, a1; llc_ld4(a0, p); llc_ld4(a1, p + 4); vwait();
        p1w(tb | mrow, a0, a1);
        float* q2 = C.mybuf + (wid << 9) + (lane << 3);
        l2_st4(q2, a0); l2_st4(q2 + 4, a1);
        pairWait(C, tid);
        const int prow = ((C.myhalf ^ 1) << 3) | wid;
        const float* pr = C.pbuf + (wid << 9) + (lane << 3);
        f32x4 b0, b1; l2_ld4(b0, pr); l2_ld4(b1, pr + 4); vwait();
        p1w(tb | prow, b0, b1);
      } else {
        const float* pa = Hr + (wid << 9) + (lane << 3);
        const float* pb = Hr + ((wid + 8) << 9) + (lane << 3);
        f32x4 a0, a1, b0, b1;
        llc_ld4(a0, pa); llc_ld4(a1, pa + 4);
        llc_ld4(b0, pb); llc_ld4(b1, pb + 4);
        vwait();
        p1w(tb | wid, a0, a1);
        p1w(tb | (wid + 8), b0, b1);
      }
      if (tid < 128) {
        const int tx = (((tid & 7) >> 2) << 6) | (tid >> 3) | ((tid & 3) << 4);
        task_write(tx, x0, x1, sXh, sXl);
      }
    }
    __syncthreads();
    {
      f32x4 acc = {0,0,0,0};
      const int ntg = (half ? 32 : 0) | ((g << 1) | nt);
      if (!mat) mm(sAh, sAl, P.Wh[0], P.Wl[0], 64, ntg, 0, 16, lane, acc);
      else      mm(sBh, sBl, P.Wh[1], P.Wl[1], 64, ntg, 0, 16, lane, acc);
      if (mat) *(f32x4*)&red[(((half << 1) | nt) << 8) | (lane << 2)] = acc;
      __syncthreads();
      if (!mat) acc += *(f32x4*)&red[(((half << 1) | nt) << 8) | (lane << 2)];
      __syncthreads();
      if (!mat && half) *(f32x4*)&red[(nt << 8) | (lane << 2)] = acc;
      __syncthreads();
      if (!mat && !half) {
        const f32x4 ar = *(const f32x4*)&red[(nt << 8) | (lane << 2)];
        #pragma unroll
        for (int i = 0; i < 4; ++i) {
          zAreg[i] = sigm(acc[i] + b_az);
          const float rA = sigm(ar[i] + b_ar);
          llc_st1(&P.NrA[((rb + i) << 9) | col5], Nreg[i] * rA);
        }
      }
    }
    gbar(P.cnt, stripe, ph);

    // ---- P2: N = (1-zA)N + zA tanh(dt@Wna + NrA@Una + bna) ---------------
    pairStage(P.NrA + (r0 << 9), sBh, sBl, C, wid, lane, tid);
    __syncthreads();
    {
      f32x4 acc = {0,0,0,0};
      const int kc0 = (q & 1) << 3;
      if (!(q >> 1)) mm(sAh, sAl, P.Wh[2], P.Wl[2], 32, ntb, kc0, kc0 + 8, lane, acc);
      else           mm(sBh, sBl, P.Wh[3], P.Wl[3], 32, ntb, kc0, kc0 + 8, lane, acc);
      if (q) *(f32x4*)&red[((((q - 1) << 1) | nt) << 8) | (lane << 2)] = acc;
      __syncthreads();
      if (!q) {
        #pragma unroll
        for (int j = 0; j < 3; ++j) acc += *(f32x4*)&red[(((j << 1) | nt) << 8) | (lane << 2)];
        #pragma unroll
        for (int i = 0; i < 4; ++i) {
          const float hn = tanhf(acc[i] + b_na);
          const float Nn = (1.f - zAreg[i]) * Nreg[i] + zAreg[i] * hn;
          Nreg[i] = Nn;
          llc_st1(&P.Nst[((rb + i) << 9) | col5], Nn);
        }
      }
    }
    gbar(P.cnt, stripe, ph);

    // ---- P3: s1 = tanh(h@WAttn + N_new@UAttn) ----------------------------
    pairStage(P.Nst + (r0 << 9), sBh, sBl, C, wid, lane, tid);  // N-new persists in sB
    __syncthreads();
    {
      f32x4 acc = {0,0,0,0};
      const int kc0 = (q & 1) << 3;
      if (!(q >> 1)) mm(sDh, sDl, P.Wh[4], P.Wl[4], 32, ntb, kc0, kc0 + 8, lane, acc);
      else           mm(sBh, sBl, P.Wh[5], P.Wl[5], 32, ntb, kc0, kc0 + 8, lane, acc);
      if (q) *(f32x4*)&red[((((q - 1) << 1) | nt) << 8) | (lane << 2)] = acc;
      __syncthreads();
      if (!q) {
        #pragma unroll
        for (int j = 0; j < 3; ++j) acc += *(f32x4*)&red[(((j << 1) | nt) << 8) | (lane << 2)];
        #pragma unroll
        for (int i = 0; i < 4; ++i)
          llc_st1(&P.s1[((rb + i) << 9) | col5], tanhf(acc[i]));
      }
    }
    gbar(P.cnt, stripe, ph);

    // ---- P4: score = s1@VAttn --------------------------------------------
    pairStage(P.s1 + (r0 << 9), sCh, sCl, C, wid, lane, tid);
    __syncthreads();
    {
      f32x4 acc = {0,0,0,0};
      mm(sCh, sCl, P.Wh[6], P.Wl[6], 32, ntb, q << 2, (q << 2) + 4, lane, acc);
      if (q) *(f32x4*)&red[((((q - 1) << 1) | nt) << 8) | (lane << 2)] = acc;
      __syncthreads();
      if (!q) {
        #pragma unroll
        for (int j = 0; j < 3; ++j) acc += *(f32x4*)&red[(((j << 1) | nt) << 8) | (lane << 2)];
        #pragma unroll
        for (int i = 0; i < 4; ++i)
          llc_st1(&P.score[((rb + i) << 9) | col5], acc[i]);
      }
    }
    gbar(P.cnt, stripe, ph);

    // ---- P5: stage score -> sA(f32); softmax+Omega -> sC; m = tanh(...) --
    {
      // relay score rows into sA-as-f32 (rows 0-7 in sAh, 8-15 in sAl)
      auto srow = [&](int r) -> float* {
        return (r < 8) ? ((float*)sAh + (r << 9)) : ((float*)sAl + ((r & 7) << 9));
      };
      const float* src = P.score + (r0 << 9);
      if (C.relay) {
        const int mrow = (C.myhalf << 3) | wid;
        const float* p = src + (mrow << 9) + (lane << 3);
        f32x4 a0, a1; llc_ld4(a0, p); llc_ld4(a1, p + 4); vwait();
        { float* d = srow(mrow) + (lane << 3); *(f32x4*)d = a0; *(f32x4*)(d + 4) = a1; }
        float* q2 = C.mybuf + (wid << 9) + (lane << 3);
        l2_st4(q2, a0); l2_st4(q2 + 4, a1);
        pairWait(C, tid);
        const int prow = ((C.myhalf ^ 1) << 3) | wid;
        const float* pr = C.pbuf + (wid << 9) + (lane << 3);
        f32x4 b0, b1; l2_ld4(b0, pr); l2_ld4(b1, pr + 4); vwait();
        { float* d = srow(prow) + (lane << 3); *(f32x4*)d = b0; *(f32x4*)(d + 4) = b1; }
      } else {
        f32x4 a0, a1, b0, b1;
        llc_ld4(a0, src + (wid << 9) + (lane << 3));
        llc_ld4(a1, src + (wid << 9) + (lane << 3) + 4);
        llc_ld4(b0, src + ((wid + 8) << 9) + (lane << 3));
        llc_ld4(b1, src + ((wid + 8) << 9) + (lane << 3) + 4);
        vwait();
        { float* d = srow(wid) + (lane << 3);     *(f32x4*)d = a0; *(f32x4*)(d + 4) = a1; }
        { float* d = srow(wid + 8) + (lane << 3); *(f32x4*)d = b0; *(f32x4*)(d + 4) = b1; }
      }
      __syncthreads();
      const int lr0 = wid << 1;
      #pragma unroll
      for (int rr = 0; rr < 2; ++rr) {
        const int lr = lr0 | rr;
        const float* sp = ((lr < 8) ? ((const float*)sAh + (lr << 9))
                                    : ((const float*)sAl + ((lr & 7) << 9))) + (lane << 3);
        const f32x4 v0 = *(const f32x4*)sp;
        const f32x4 v1 = *(const f32x4*)(sp + 4);
        float mx = v0[0];
        #pragma unroll
        for (int j = 1; j < 4; ++j) mx = fmaxf(mx, v0[j]);
        #pragma unroll
        for (int j = 0; j < 4; ++j) mx = fmaxf(mx, v1[j]);
        #pragma unroll
        for (int d = 1; d < 64; d <<= 1) mx = fmaxf(mx, __shfl_xor(mx, d));
        float e[8];
        #pragma unroll
        for (int j = 0; j < 4; ++j) { e[j] = expf(v0[j] - mx); e[j + 4] = expf(v1[j] - mx); }
        float sm = ((e[0] + e[1]) + (e[2] + e[3])) + ((e[4] + e[5]) + (e[6] + e[7]));
        #pragma unroll
        for (int d = 1; d < 64; d <<= 1) sm += __shfl_xor(sm, d);
        const float inv = 1.f / sm;
        const int o = aoff(((lane >> 2) << 6) | lr | ((lane & 3) << 4));
        const bf16x8 nh = *(const bf16x8*)(sBh + o), nl = *(const bf16x8*)(sBl + o);
        bf16x8 vh, vl;
        #pragma unroll
        for (int j = 0; j < 8; ++j) {
          const float om = e[j] * inv * (bf2f(nh[j]) + bf2f(nl[j]));
          const short hb = f2bf(om);
          vh[j] = hb; vl[j] = f2bf(om - bf2f(hb));
        }
        *(bf16x8*)(sCh + o) = vh;
        *(bf16x8*)(sCl + o) = vl;
      }
    }
    __syncthreads();
    {
      f32x4 acc = {0,0,0,0};
      const int kc0 = (q & 1) << 3;
      if (!(q >> 1)) mm(sCh, sCl, P.Wh[7], P.Wl[7], 32, ntb, kc0, kc0 + 8, lane, acc);
      else           mm(sDh, sDl, P.Wh[8], P.Wl[8], 32, ntb, kc0, kc0 + 8, lane, acc);
      if (q) *(f32x4*)&red[((((q - 1) << 1) | nt) << 8) | (lane << 2)] = acc;
      __syncthreads();
      if (!q) {
        #pragma unroll
        for (int j = 0; j < 3; ++j) acc += *(f32x4*)&red[(((j << 1) | nt) << 8) | (lane << 2)];
        #pragma unroll
        for (int i = 0; i < 4; ++i) {
          const float m = tanhf(acc[i] + b_ma);
          mreg[i] = m;
          llc_st1(&P.mbuf[((rb + i) << 9) | col5], m);
        }
      }
    }
    gbar(P.cnt, stripe, ph);

    // ---- P6: gates_M = x@Wm + m@Um -> zM(reg), mrM(global) ---------------
    pairStage(P.mbuf + (r0 << 9), sAh, sAl, C, wid, lane, tid);
    __syncthreads();
    {
      f32x4 acc = {0,0,0,0};
      const int ntg = (half ? 32 : 0) | ((g << 1) | nt);
      if (!mat) { mm(sXh, sXl, P.Wh[9],  P.Wl[9],  64, ntg, 0, 2, lane, acc);
                  mm(sAh, sAl, P.Wh[10], P.Wl[10], 64, ntg, 0, 7, lane, acc); }
      else      { mm(sAh, sAl, P.Wh[10], P.Wl[10], 64, ntg, 7, 16, lane, acc); }
      if (mat) *(f32x4*)&red[(((half << 1) | nt) << 8) | (lane << 2)] = acc;
      __syncthreads();
      if (!mat) acc += *(f32x4*)&red[(((half << 1) | nt) << 8) | (lane << 2)];
      __syncthreads();
      if (!mat && half) *(f32x4*)&red[(nt << 8) | (lane << 2)] = acc;
      __syncthreads();
      if (!mat && !half) {
        const f32x4 ar = *(const f32x4*)&red[(nt << 8) | (lane << 2)];
        #pragma unroll
        for (int i = 0; i < 4; ++i) {
          zMreg[i] = sigm(acc[i] + b_mz);
          const float rM = sigm(ar[i] + b_mr);
          llc_st1(&P.mrM[((rb + i) << 9) | col5], mreg[i] * rM);
        }
      }
    }
    gbar(P.cnt, stripe, ph);

    // ---- P7: h = (1-zM)h + zM tanh(x@Whm + mrM@Uhm + bhm) ----------------
    pairStage(P.mrM + (r0 << 9), sCh, sCl, C, wid, lane, tid);
    __syncthreads();
    {
      f32x4 acc = {0,0,0,0};
      if (q == 0)      { mm(sXh, sXl, P.Wh[11], P.Wl[11], 32, ntb, 0, 2, lane, acc);
                         mm(sCh, sCl, P.Wh[12], P.Wl[12], 32, ntb, 0, 2, lane, acc); }
      else if (q == 1)   mm(sCh, sCl, P.Wh[12], P.Wl[12], 32, ntb, 2, 7, lane, acc);
      else if (q == 2)   mm(sCh, sCl, P.Wh[12], P.Wl[12], 32, ntb, 7, 12, lane, acc);
      else               mm(sCh, sCl, P.Wh[12], P.Wl[12], 32, ntb, 12, 16, lane, acc);
      if (q) *(f32x4*)&red[((((q - 1) << 1) | nt) << 8) | (lane << 2)] = acc;
      __syncthreads();
      if (!q) {
        #pragma unroll
        for (int j = 0; j < 3; ++j) acc += *(f32x4*)&red[(((j << 1) | nt) << 8) | (lane << 2)];
        #pragma unroll
        for (int i = 0; i < 4; ++i) {
          const float hh = tanhf(acc[i] + b_hm);
          const float hn = (1.f - zMreg[i]) * hreg[i] + zMreg[i] * hh;
          hreg[i] = hn;
          llc_st1(&P.Hbuf[((rb + i) << 9) | col5], hn);
          P.out[((((size_t)(rb + i)) << 8 | t) << 9) | col5] = hn;
        }
      }
    }
    gbar(P.cnt, stripe, ph);
  }
}

__global__ __launch_bounds__(256)
void initk(float* hbuf, unsigned* cnt) {
  const int i = blockIdx.x * 256 + threadIdx.x;
  hbuf[i] = 0.f;
  if (blockIdx.x < 16) cnt[blockIdx.x * 256 + threadIdx.x] = 0u;
}

__global__ __launch_bounds__(256)
void finalize(const float* __restrict__ hT, const float* __restrict__ nT,
              float* __restrict__ oh, float* __restrict__ on) {
  const int i = blockIdx.x * 256 + threadIdx.x;
  f32x4 a, b;
  asm volatile("global_load_dword %0, %1, off sc0 sc1" : "=v"(a[0]) : "v"(&hT[i]));
  asm volatile("global_load_dword %0, %1, off sc0 sc1" : "=v"(b[0]) : "v"(&nT[i]));
  vwait();
  oh[i] = a[0]; on[i] = b[0];
}

extern "C" void kernel_launch(void* const* d_in, const int* in_sizes, int n_in,
                              void* d_out, int out_size, void* d_ws, size_t ws_size,
                              hipStream_t stream)
{
  (void)in_sizes; (void)n_in; (void)out_size; (void)ws_size;

  unsigned* cnt = (unsigned*)d_ws;          // 16KB: barrier + pair flags/info
  float* w = (float*)d_ws + 4096;
  const int S = Bsz * Hd;                   // 131072

  KP P{};
  P.x   = (const float*)d_in[0];
  P.ba  = (const float*)d_in[3];
  P.bna = (const float*)d_in[6];
  P.bma = (const float*)d_in[12];
  P.bm  = (const float*)d_in[15];
  P.bhm = (const float*)d_in[18];
  P.Hbuf = w;          P.Nst = w + S;      P.NrA = w + 2 * S;
  P.s1   = w + 3 * S;  P.score = w + 4 * S;
  P.mbuf = w + 5 * S;  P.mrM = w + 6 * S;
  P.out = (float*)d_out;
  P.cnt = cnt;
  float* out_hT = P.out + (size_t)Bsz * Tseq * Hd;
  float* out_NT = out_hT + S;

  short* wpk = (short*)(w + 7 * S);
  const int widx[13] = {1, 2, 4, 5, 7, 8, 9, 10, 11, 13, 14, 16, 17};
  const int wK[13]   = {512, 512, 512, 512, 512, 512, 512, 512, 512, 64, 512, 64, 512};
  const int wN[13]   = {1024, 1024, 512, 512, 512, 512, 512, 512, 512, 1024, 1024, 512, 512};
  size_t woff = 0;
  for (int i = 0; i < 13; ++i) {
    const size_t sz = (size_t)wK[i] * wN[i];
    P.Wh[i] = wpk + woff; woff += sz;
    P.Wl[i] = wpk + woff; woff += sz;
  }
  P.pairbuf = (float*)(wpk + woff);         // 128 pairs x 2 halves x 16KB = 4MB

  for (int i = 0; i < 13; ++i) {
    dim3 gg(wN[i] / 256, wK[i] / 32);
    prepack<<<gg, 256, 0, stream>>>((const float*)d_in[widx[i]],
                                    (short*)P.Wh[i], (short*)P.Wl[i], wN[i]);
  }

  initk<<<S / 256, 256, 0, stream>>>(P.Hbuf, cnt);

  dtgru<<<NBLK, NTHR, 0, stream>>>(P);

  finalize<<<S / 256, 256, 0, stream>>>(P.Hbuf, P.Nst, out_hT, out_NT);
}

// Round 13
// 18179.135 us; speedup vs baseline: 1.2416x; 1.1946x over previous
//
#include <hip/hip_runtime.h>

static constexpr int Bsz  = 256;   // batch
static constexpr int Tseq = 256;   // timesteps
static constexpr int Hd   = 512;   // d_model
static constexpr int Ein  = 64;    // enc_in
static constexpr int NBLK = 256;   // 16 stripes x 16 colgroups
static constexpr int NTHR = 512;   // 8 waves

typedef __attribute__((ext_vector_type(8))) short bf16x8;
typedef __attribute__((ext_vector_type(4))) float f32x4;
typedef __attribute__((ext_vector_type(8))) _Float16 f16x8;
typedef unsigned long long u64;

__device__ __forceinline__ float sigm(float x) { return 1.f / (1.f + expf(-x)); }
__device__ __forceinline__ short f2bf(float f) {
  union { float f; unsigned u; } v; v.f = f;
  unsigned r = v.u + 0x7FFFu + ((v.u >> 16) & 1u);
  return (short)(r >> 16);
}
__device__ __forceinline__ float bf2f(short s) {
  union { float f; unsigned u; } v; v.u = ((unsigned)(unsigned short)s) << 16; return v.f;
}

// ---- LLC-coherent (sc0 sc1): bypass L1/L2, serialize at LLC ----------------
__device__ __forceinline__ void llc_ld8h(f16x8& d, const _Float16* p) {
  asm volatile("global_load_dwordx4 %0, %1, off sc0 sc1" : "=v"(d) : "v"(p));
}
__device__ __forceinline__ void llc_sth(_Float16* p, _Float16 v) {
  asm volatile("global_store_short %0, %1, off sc0 sc1" :: "v"(p), "v"(v) : "memory");
}
__device__ __forceinline__ void vwait() {
  asm volatile("s_waitcnt vmcnt(0)" ::: "memory");
  __builtin_amdgcn_sched_barrier(0);
}

struct KP {
  const float *x, *ba, *bna, *bma, *bm, *bhm;
  const short *Wh[13], *Wl[13];  // 0 Wa,1 Ua,2 Wna,3 Una,4 WAt,5 UAt,6 VAt,7 Wma,8 Uma,9 Wm,10 Um,11 Whm,12 Uhm
  _Float16 *Hbuf, *Nst, *NrA, *s1, *score, *mbuf, *mrM;
  float* out;
  unsigned* cnt;
};

// ---------------------------------------------------------------------------
// Weight prepack (verified r4-r12): fp32 [K][N] -> fragment-major bf16 hi/lo.
// ---------------------------------------------------------------------------
__global__ __launch_bounds__(256)
void prepack(const float* __restrict__ W, short* __restrict__ Whi,
             short* __restrict__ Wlo, int N)
{
  __shared__ float lds[32][257];
  const int tid = threadIdx.x;
  const int k0 = blockIdx.y * 32;
  const int n0 = blockIdx.x * 256;
  #pragma unroll
  for (int i = 0; i < 8; ++i) {
    const int flat = (i * 256 + tid) * 4;
    const int r = flat >> 8, c = flat & 255;
    const float4 v = *(const float4*)(W + (size_t)(k0 + r) * N + n0 + c);
    lds[r][c] = v.x; lds[r][c + 1] = v.y; lds[r][c + 2] = v.z; lds[r][c + 3] = v.w;
  }
  __syncthreads();
  const int lane = tid & 63, wv = tid >> 6;
  const int kr = (lane >> 4) * 8;
  const int cc = lane & 15;
  for (int nt = wv; nt < 16; nt += 4) {
    const int ntg = (n0 >> 4) + nt;
    const size_t off = ((size_t)((k0 >> 5) * (N >> 4) + ntg) * 64 + lane) * 8;
    bf16x8 vh, vl;
    #pragma unroll
    for (int j = 0; j < 8; ++j) {
      const float v = lds[kr + j][nt * 16 + cc];
      const short hb = f2bf(v);
      vh[j] = hb; vl[j] = f2bf(v - bf2f(hb));
    }
    *(bf16x8*)(Whi + off) = vh;
    *(bf16x8*)(Wlo + off) = vl;
  }
}

// Fragment task map: task=(kc<<6)|dl, element (row=dl&15, k=kc*32+((dl>>4)<<3)+j)
__device__ __forceinline__ void task_write(int task, f32x4 u0, f32x4 u1,
                                           short* hi, short* lo) {
  const int o = task << 3;
  bf16x8 vh, vl;
  #pragma unroll
  for (int j = 0; j < 4; ++j) {
    const short h0 = f2bf(u0[j]); vh[j]     = h0; vl[j]     = f2bf(u0[j] - bf2f(h0));
    const short h1 = f2bf(u1[j]); vh[j + 4] = h1; vl[j + 4] = f2bf(u1[j] - bf2f(h1));
  }
  *(bf16x8*)(hi + o) = vh;
  *(bf16x8*)(lo + o) = vl;
}
__device__ __forceinline__ void h2f8(f16x8 v, f32x4& a0, f32x4& a1) {
  #pragma unroll
  for (int j = 0; j < 4; ++j) { a0[j] = (float)v[j]; a1[j] = (float)v[j + 4]; }
}

// Stage one 16x512 fp16 slice (16KB, contiguous 1KB rows): wave w loads rows
// w and w+8; lane l owns k = l*8..l*8+7 -> task ((l>>2)<<6)|row|((l&3)<<4).
__device__ __forceinline__ void stageSlice(const _Float16* src, short* hi, short* lo,
                                           int wid, int lane) {
  f16x8 a, b;
  llc_ld8h(a, src + (wid << 9) + (lane << 3));
  llc_ld8h(b, src + ((wid + 8) << 9) + (lane << 3));
  vwait();
  const int tb = ((lane >> 2) << 6) | ((lane & 3) << 4);
  f32x4 a0, a1, b0, b1;
  h2f8(a, a0, a1); h2f8(b, b0, b1);
  task_write(tb | wid, a0, a1, hi, lo);
  task_write(tb | (wid + 8), b0, b1, hi, lo);
}

// MFMA over kc range, 3-term hi/lo split (~operand-exact on fp16 inputs).
__device__ __forceinline__ void mm(const short* Ah, const short* Al,
                                   const short* __restrict__ Wh,
                                   const short* __restrict__ Wl,
                                   int ntN, int ntg, int kc0, int kc1,
                                   int lane, f32x4& acc)
{
  for (int kc = kc0; kc < kc1; ++kc) {
    const int ao = ((kc << 6) | lane) << 3;
    const bf16x8 ah = *(const bf16x8*)(Ah + ao);
    const bf16x8 al = *(const bf16x8*)(Al + ao);
    const size_t o = ((size_t)((kc * ntN + ntg) << 6 | lane)) << 3;
    const bf16x8 bh = *(const bf16x8*)(Wh + o);
    const bf16x8 bl = *(const bf16x8*)(Wl + o);
    acc = __builtin_amdgcn_mfma_f32_16x16x32_bf16(ah, bh, acc, 0, 0, 0);
    acc = __builtin_amdgcn_mfma_f32_16x16x32_bf16(al, bh, acc, 0, 0, 0);
    acc = __builtin_amdgcn_mfma_f32_16x16x32_bf16(ah, bl, acc, 0, 0, 0);
  }
}

// Per-stripe barrier (r10-verified): 16 blocks, relaxed atomics, s_sleep(4).
__device__ __forceinline__ void gbar(unsigned* cnt, int stripe, unsigned& ph) {
  asm volatile("s_waitcnt vmcnt(0)" ::: "memory");
  __syncthreads();
  ++ph;
  if (threadIdx.x == 0) {
    __hip_atomic_fetch_add(&cnt[stripe << 4], 1u, __ATOMIC_RELAXED,
                           __HIP_MEMORY_SCOPE_AGENT);
    const unsigned tgt = ph * 16u;
    while (__hip_atomic_load(&cnt[stripe << 4], __ATOMIC_RELAXED,
                             __HIP_MEMORY_SCOPE_AGENT) < tgt)
      __builtin_amdgcn_s_sleep(4);
  }
  __syncthreads();
}

// ---------------------------------------------------------------------------
// Persistent kernel: 256 blocks = 16 stripes(16 rows) x 16 colgroups(32 cols).
// fp16 inter-block state; LDS-resident h(sD)/N(sB); reg zA/zM/m/N/h.
// ---------------------------------------------------------------------------
__global__ __launch_bounds__(NTHR, 1)
void dtgru(KP P)
{
  __shared__ short sAh[8192], sAl[8192];   // dt (P1-P2) / m (P6)
  __shared__ short sBh[8192], sBl[8192];   // N (P1,P5) / NrA (P2) / N-new (P3..)
  __shared__ short sCh[8192], sCl[8192];   // s1 (P4) / Omega (P5) / mrM (P7)
  __shared__ short sDh[8192], sDl[8192];   // h(t-1) [persists]
  __shared__ short sXh[1024], sXl[1024];   // x_t
  __shared__ float red[2048];
  const int tid = threadIdx.x, lane = tid & 63, wid = tid >> 6;
  const int bid = blockIdx.x;
  const int g = bid & 15;
  const int stripe = bid >> 4;
  const int r0 = stripe << 4;
  const int nt = wid & 1;
  const int q  = wid >> 1;
  const int mat  = (wid >> 1) & 1;
  const int half = wid >> 2;
  const int ntb = (g << 1) | nt;
  const int col5 = (g << 5) | (nt << 4) | (lane & 15);
  const int rb = r0 + ((lane >> 4) << 2);
  unsigned ph = 0;
  float Nreg[4] = {0,0,0,0}, hreg[4] = {0,0,0,0};
  float zAreg[4] = {0,0,0,0}, zMreg[4] = {0,0,0,0}, mreg[4] = {0,0,0,0};
  const float b_az = P.ba[col5],  b_ar = P.ba[col5 + 512];
  const float b_na = P.bna[col5], b_ma = P.bma[col5];
  const float b_mz = P.bm[col5],  b_mr = P.bm[col5 + 512];
  const float b_hm = P.bhm[col5];

  for (int i = tid; i < 2048; i += NTHR) {       // zero persistent slots (B, D)
    ((u64*)sBh)[i] = 0; ((u64*)sBl)[i] = 0;
    ((u64*)sDh)[i] = 0; ((u64*)sDl)[i] = 0;
  }
  __syncthreads();

  #pragma clang loop unroll(disable)
  for (int t = 0; t < Tseq; ++t) {
    // ---- P1: gates_A = dt@Wa + N@Ua -> zA(reg), NrA(global) --------------
    {
      const _Float16* Hr = P.Hbuf + (r0 << 9);
      f16x8 ha, hb;
      llc_ld8h(ha, Hr + (wid << 9) + (lane << 3));
      llc_ld8h(hb, Hr + ((wid + 8) << 9) + (lane << 3));
      f32x4 x0 = {0,0,0,0}, x1 = {0,0,0,0};
      if (tid < 128) {                            // x: normal cached loads
        const float* px = P.x + ((size_t)(r0 + (tid >> 3)) * Tseq + t) * Ein
                        + ((tid & 7) << 3);
        x0 = *(const f32x4*)px; x1 = *(const f32x4*)(px + 4);
      }
      vwait();
      const int tb = ((lane >> 2) << 6) | ((lane & 3) << 4);
      auto p1w = [&](int task, f16x8 hv) {
        const int o = task << 3;
        f32x4 u0, u1; h2f8(hv, u0, u1);
        const bf16x8 dh = *(const bf16x8*)(sDh + o), dlo = *(const bf16x8*)(sDl + o);
        f32x4 d0, d1;
        #pragma unroll
        for (int j = 0; j < 4; ++j) {
          d0[j] = u0[j] - (bf2f(dh[j])     + bf2f(dlo[j]));
          d1[j] = u1[j] - (bf2f(dh[j + 4]) + bf2f(dlo[j + 4]));
        }
        task_write(task, d0, d1, sAh, sAl);
        task_write(task, u0, u1, sDh, sDl);
      };
      p1w(tb | wid, ha);
      p1w(tb | (wid + 8), hb);
      if (tid < 128) {
        const int tx = (((tid & 7) >> 2) << 6) | (tid >> 3) | ((tid & 3) << 4);
        task_write(tx, x0, x1, sXh, sXl);
      }
    }
    __syncthreads();
    {
      f32x4 acc = {0,0,0,0};
      const int ntg = (half ? 32 : 0) | ((g << 1) | nt);
      if (!mat) mm(sAh, sAl, P.Wh[0], P.Wl[0], 64, ntg, 0, 16, lane, acc);
      else      mm(sBh, sBl, P.Wh[1], P.Wl[1], 64, ntg, 0, 16, lane, acc);
      if (mat) *(f32x4*)&red[(((half << 1) | nt) << 8) | (lane << 2)] = acc;
      __syncthreads();
      if (!mat) acc += *(f32x4*)&red[(((half << 1) | nt) << 8) | (lane << 2)];
      __syncthreads();
      if (!mat && half) *(f32x4*)&red[(nt << 8) | (lane << 2)] = acc;
      __syncthreads();
      if (!mat && !half) {
        const f32x4 ar = *(const f32x4*)&red[(nt << 8) | (lane << 2)];
        #pragma unroll
        for (int i = 0; i < 4; ++i) {
          zAreg[i] = sigm(acc[i] + b_az);
          const float rA = sigm(ar[i] + b_ar);
          llc_sth(&P.NrA[((rb + i) << 9) | col5], (_Float16)(Nreg[i] * rA));
        }
      }
    }
    gbar(P.cnt, stripe, ph);

    // ---- P2: N = (1-zA)N + zA tanh(dt@Wna + NrA@Una + bna) ---------------
    stageSlice(P.NrA + (r0 << 9), sBh, sBl, wid, lane);
    __syncthreads();
    {
      f32x4 acc = {0,0,0,0};
      const int kc0 = (q & 1) << 3;
      if (!(q >> 1)) mm(sAh, sAl, P.Wh[2], P.Wl[2], 32, ntb, kc0, kc0 + 8, lane, acc);
      else           mm(sBh, sBl, P.Wh[3], P.Wl[3], 32, ntb, kc0, kc0 + 8, lane, acc);
      if (q) *(f32x4*)&red[((((q - 1) << 1) | nt) << 8) | (lane << 2)] = acc;
      __syncthreads();
      if (!q) {
        #pragma unroll
        for (int j = 0; j < 3; ++j) acc += *(f32x4*)&red[(((j << 1) | nt) << 8) | (lane << 2)];
        #pragma unroll
        for (int i = 0; i < 4; ++i) {
          const float hn = tanhf(acc[i] + b_na);
          const float Nn = (1.f - zAreg[i]) * Nreg[i] + zAreg[i] * hn;
          Nreg[i] = Nn;
          llc_sth(&P.Nst[((rb + i) << 9) | col5], (_Float16)Nn);
        }
      }
    }
    gbar(P.cnt, stripe, ph);

    // ---- P3: s1 = tanh(h@WAttn + N_new@UAttn) ----------------------------
    stageSlice(P.Nst + (r0 << 9), sBh, sBl, wid, lane);  // N-new -> sB (persists)
    __syncthreads();
    {
      f32x4 acc = {0,0,0,0};
      const int kc0 = (q & 1) << 3;
      if (!(q >> 1)) mm(sDh, sDl, P.Wh[4], P.Wl[4], 32, ntb, kc0, kc0 + 8, lane, acc);
      else           mm(sBh, sBl, P.Wh[5], P.Wl[5], 32, ntb, kc0, kc0 + 8, lane, acc);
      if (q) *(f32x4*)&red[((((q - 1) << 1) | nt) << 8) | (lane << 2)] = acc;
      __syncthreads();
      if (!q) {
        #pragma unroll
        for (int j = 0; j < 3; ++j) acc += *(f32x4*)&red[(((j << 1) | nt) << 8) | (lane << 2)];
        #pragma unroll
        for (int i = 0; i < 4; ++i)
          llc_sth(&P.s1[((rb + i) << 9) | col5], (_Float16)tanhf(acc[i]));
      }
    }
    gbar(P.cnt, stripe, ph);

    // ---- P4: score = s1@VAttn --------------------------------------------
    stageSlice(P.s1 + (r0 << 9), sCh, sCl, wid, lane);
    __syncthreads();
    {
      f32x4 acc = {0,0,0,0};
      mm(sCh, sCl, P.Wh[6], P.Wl[6], 32, ntb, q << 2, (q << 2) + 4, lane, acc);
      if (q) *(f32x4*)&red[((((q - 1) << 1) | nt) << 8) | (lane << 2)] = acc;
      __syncthreads();
      if (!q) {
        #pragma unroll
        for (int j = 0; j < 3; ++j) acc += *(f32x4*)&red[(((j << 1) | nt) << 8) | (lane << 2)];
        #pragma unroll
        for (int i = 0; i < 4; ++i)
          llc_sth(&P.score[((rb + i) << 9) | col5], (_Float16)acc[i]);
      }
    }
    gbar(P.cnt, stripe, ph);

    // ---- P5: softmax+Omega (N from sB, Omega -> sC); m = tanh(...) -------
    {
      const int lr0 = wid << 1;
      f16x8 s0v, s1v;
      llc_ld8h(s0v, P.score + ((r0 + lr0) << 9) + (lane << 3));
      llc_ld8h(s1v, P.score + ((r0 + lr0 + 1) << 9) + (lane << 3));
      vwait();
      #pragma unroll
      for (int rr = 0; rr < 2; ++rr) {
        const int lr = lr0 | rr;
        f32x4 v0, v1; h2f8(rr ? s1v : s0v, v0, v1);
        float mx = v0[0];
        #pragma unroll
        for (int j = 1; j < 4; ++j) mx = fmaxf(mx, v0[j]);
        #pragma unroll
        for (int j = 0; j < 4; ++j) mx = fmaxf(mx, v1[j]);
        #pragma unroll
        for (int d = 1; d < 64; d <<= 1) mx = fmaxf(mx, __shfl_xor(mx, d));
        float e[8];
        #pragma unroll
        for (int j = 0; j < 4; ++j) { e[j] = expf(v0[j] - mx); e[j + 4] = expf(v1[j] - mx); }
        float sm = ((e[0] + e[1]) + (e[2] + e[3])) + ((e[4] + e[5]) + (e[6] + e[7]));
        #pragma unroll
        for (int d = 1; d < 64; d <<= 1) sm += __shfl_xor(sm, d);
        const float inv = 1.f / sm;
        const int o = (((lane >> 2) << 6) | lr | ((lane & 3) << 4)) << 3;
        const bf16x8 nh = *(const bf16x8*)(sBh + o), nl = *(const bf16x8*)(sBl + o);
        bf16x8 vh, vl;
        #pragma unroll
        for (int j = 0; j < 8; ++j) {
          const float om = e[j] * inv * (bf2f(nh[j]) + bf2f(nl[j]));
          const short hb = f2bf(om);
          vh[j] = hb; vl[j] = f2bf(om - bf2f(hb));
        }
        *(bf16x8*)(sCh + o) = vh;
        *(bf16x8*)(sCl + o) = vl;
      }
    }
    __syncthreads();
    {
      f32x4 acc = {0,0,0,0};
      const int kc0 = (q & 1) << 3;
      if (!(q >> 1)) mm(sCh, sCl, P.Wh[7], P.Wl[7], 32, ntb, kc0, kc0 + 8, lane, acc);
      else           mm(sDh, sDl, P.Wh[8], P.Wl[8], 32, ntb, kc0, kc0 + 8, lane, acc);
      if (q) *(f32x4*)&red[((((q - 1) << 1) | nt) << 8) | (lane << 2)] = acc;
      __syncthreads();
      if (!q) {
        #pragma unroll
        for (int j = 0; j < 3; ++j) acc += *(f32x4*)&red[(((j << 1) | nt) << 8) | (lane << 2)];
        #pragma unroll
        for (int i = 0; i < 4; ++i) {
          const float m = tanhf(acc[i] + b_ma);
          mreg[i] = m;
          llc_sth(&P.mbuf[((rb + i) << 9) | col5], (_Float16)m);
        }
      }
    }
    gbar(P.cnt, stripe, ph);

    // ---- P6: gates_M = x@Wm + m@Um -> zM(reg), mrM(global) ---------------
    stageSlice(P.mbuf + (r0 << 9), sAh, sAl, wid, lane);
    __syncthreads();
    {
      f32x4 acc = {0,0,0,0};
      const int ntg = (half ? 32 : 0) | ((g << 1) | nt);
      if (!mat) { mm(sXh, sXl, P.Wh[9],  P.Wl[9],  64, ntg, 0, 2, lane, acc);
                  mm(sAh, sAl, P.Wh[10], P.Wl[10], 64, ntg, 0, 7, lane, acc); }
      else      { mm(sAh, sAl, P.Wh[10], P.Wl[10], 64, ntg, 7, 16, lane, acc); }
      if (mat) *(f32x4*)&red[(((half << 1) | nt) << 8) | (lane << 2)] = acc;
      __syncthreads();
      if (!mat) acc += *(f32x4*)&red[(((half << 1) | nt) << 8) | (lane << 2)];
      __syncthreads();
      if (!mat && half) *(f32x4*)&red[(nt << 8) | (lane << 2)] = acc;
      __syncthreads();
      if (!mat && !half) {
        const f32x4 ar = *(const f32x4*)&red[(nt << 8) | (lane << 2)];
        #pragma unroll
        for (int i = 0; i < 4; ++i) {
          zMreg[i] = sigm(acc[i] + b_mz);
          const float rM = sigm(ar[i] + b_mr);
          llc_sth(&P.mrM[((rb + i) << 9) | col5], (_Float16)(mreg[i] * rM));
        }
      }
    }
    gbar(P.cnt, stripe, ph);

    // ---- P7: h = (1-zM)h + zM tanh(x@Whm + mrM@Uhm + bhm) ----------------
    stageSlice(P.mrM + (r0 << 9), sCh, sCl, wid, lane);
    __syncthreads();
    {
      f32x4 acc = {0,0,0,0};
      if (q == 0)      { mm(sXh, sXl, P.Wh[11], P.Wl[11], 32, ntb, 0, 2, lane, acc);
                         mm(sCh, sCl, P.Wh[12], P.Wl[12], 32, ntb, 0, 2, lane, acc); }
      else if (q == 1)   mm(sCh, sCl, P.Wh[12], P.Wl[12], 32, ntb, 2, 7, lane, acc);
      else if (q == 2)   mm(sCh, sCl, P.Wh[12], P.Wl[12], 32, ntb, 7, 12, lane, acc);
      else               mm(sCh, sCl, P.Wh[12], P.Wl[12], 32, ntb, 12, 16, lane, acc);
      if (q) *(f32x4*)&red[((((q - 1) << 1) | nt) << 8) | (lane << 2)] = acc;
      __syncthreads();
      if (!q) {
        #pragma unroll
        for (int j = 0; j < 3; ++j) acc += *(f32x4*)&red[(((j << 1) | nt) << 8) | (lane << 2)];
        #pragma unroll
        for (int i = 0; i < 4; ++i) {
          const float hh = tanhf(acc[i] + b_hm);
          const float hn = (1.f - zMreg[i]) * hreg[i] + zMreg[i] * hh;
          hreg[i] = hn;
          llc_sth(&P.Hbuf[((rb + i) << 9) | col5], (_Float16)hn);
          P.out[((((size_t)(rb + i)) << 8 | t) << 9) | col5] = hn;
        }
      }
    }
    gbar(P.cnt, stripe, ph);
  }
}

__global__ __launch_bounds__(256)
void initk(_Float16* hbuf, unsigned* cnt) {
  const int i = blockIdx.x * 256 + threadIdx.x;
  hbuf[i] = (_Float16)0.f;
  if (blockIdx.x == 0) cnt[threadIdx.x] = 0u;
}

__global__ __launch_bounds__(256)
void finalize(const _Float16* __restrict__ hT, const _Float16* __restrict__ nT,
              float* __restrict__ oh, float* __restrict__ on) {
  const int i = blockIdx.x * 256 + threadIdx.x;
  unsigned a, b;
  asm volatile("global_load_ushort %0, %1, off sc0 sc1" : "=v"(a) : "v"(&hT[i]));
  asm volatile("global_load_ushort %0, %1, off sc0 sc1" : "=v"(b) : "v"(&nT[i]));
  vwait();
  unsigned short ua = (unsigned short)a, ub = (unsigned short)b;
  _Float16 ha, hb;
  __builtin_memcpy(&ha, &ua, 2); __builtin_memcpy(&hb, &ub, 2);
  oh[i] = (float)ha; on[i] = (float)hb;
}

extern "C" void kernel_launch(void* const* d_in, const int* in_sizes, int n_in,
                              void* d_out, int out_size, void* d_ws, size_t ws_size,
                              hipStream_t stream)
{
  (void)in_sizes; (void)n_in; (void)out_size; (void)ws_size;

  unsigned* cnt = (unsigned*)d_ws;          // 16 stripe counters, 64B apart
  _Float16* hw = (_Float16*)((unsigned*)d_ws + 256);
  const int S = Bsz * Hd;                   // 131072

  KP P{};
  P.x   = (const float*)d_in[0];
  P.ba  = (const float*)d_in[3];
  P.bna = (const float*)d_in[6];
  P.bma = (const float*)d_in[12];
  P.bm  = (const float*)d_in[15];
  P.bhm = (const float*)d_in[18];
  P.Hbuf = hw;          P.Nst = hw + S;      P.NrA = hw + 2 * S;
  P.s1   = hw + 3 * S;  P.score = hw + 4 * S;
  P.mbuf = hw + 5 * S;  P.mrM = hw + 6 * S;
  P.out = (float*)d_out;
  P.cnt = cnt;
  float* out_hT = P.out + (size_t)Bsz * Tseq * Hd;
  float* out_NT = out_hT + S;

  short* wpk = (short*)(hw + 7 * S);
  const int widx[13] = {1, 2, 4, 5, 7, 8, 9, 10, 11, 13, 14, 16, 17};
  const int wK[13]   = {512, 512, 512, 512, 512, 512, 512, 512, 512, 64, 512, 64, 512};
  const int wN[13]   = {1024, 1024, 512, 512, 512, 512, 512, 512, 512, 1024, 1024, 512, 512};
  {
    size_t off = 0;
    for (int i = 0; i < 13; ++i) {
      const size_t sz = (size_t)wK[i] * wN[i];
      P.Wh[i] = wpk + off; off += sz;
      P.Wl[i] = wpk + off; off += sz;
    }
  }
  for (int i = 0; i < 13; ++i) {
    dim3 gg(wN[i] / 256, wK[i] / 32);
    prepack<<<gg, 256, 0, stream>>>((const float*)d_in[widx[i]],
                                    (short*)P.Wh[i], (short*)P.Wl[i], wN[i]);
  }

  initk<<<S / 256, 256, 0, stream>>>(P.Hbuf, cnt);

  dtgru<<<NBLK, NTHR, 0, stream>>>(P);

  finalize<<<S / 256, 256, 0, stream>>>(P.Hbuf, P.Nst, out_hT, out_NT);
}